// Round 1
// 6303.190 us; speedup vs baseline: 2.2195x; 2.2195x over previous
//
#include <hip/hip_runtime.h>
#include <math.h>

#define HH 64
#define WW 64
#define NB 8
#define CIN 32
#define COUT 32
#define NT 50
#define HW (HH*WW)
#define CSX ((size_t)NT*HW)   // X channel stride
#define PITCH 20              // LDS pitch per pixel (16 ch + 4 pad), 16B-aligned, 8-group bank spread

__device__ __forceinline__ float fsigmoid(float x) {
    return 1.0f / (1.0f + __expf(-x));
}
__device__ __forceinline__ float ftanh(float x) {
    float e = __expf(-2.0f * fabsf(x));
    float t = (1.0f - e) / (1.0f + e);
    return copysignf(t, x);
}

// Weight layouts (built once):
//  Wxt[((k*32+ci)*8+cg)*16 + g*4+o]  (g=0..3 gates, o=0..3 ch within group cg)
//  Wyt[((k*32+ci)*8+cg)*12 + g*4+o]  (g=0..2)
//  Wzt[((k*32+ci)*8+cg)*4  + o]
// -> per (k,ci,cg) the weights are CONTIGUOUS: wave-uniform s_load_dwordx4/x8/x16
__global__ __launch_bounds__(256) void wtrans(
    const float* __restrict__ Wx, const float* __restrict__ Wy, const float* __restrict__ Wz,
    float* __restrict__ Wxt, float* __restrict__ Wyt, float* __restrict__ Wzt)
{
    int i = blockIdx.x * 256 + threadIdx.x;
    if (i < 36864) {               // 2304 * 16
        int g = (i >> 2) & 3, o = i & 3;
        int q = i >> 4;            // (k*32+ci)*8+cg
        int cg = q & 7, t2 = q >> 3;
        int ci = t2 & 31, k = t2 >> 5;
        int oc = g*32 + cg*4 + o;
        Wxt[i] = Wx[((size_t)oc*32 + ci)*9 + k];
    }
    if (i < 27648) {               // 2304 * 12
        int r12 = i % 12, q = i / 12;
        int g = r12 >> 2, o = r12 & 3;
        int cg = q & 7, t2 = q >> 3;
        int ci = t2 & 31, k = t2 >> 5;
        int oc = g*32 + cg*4 + o;
        Wyt[i] = Wy[((size_t)oc*32 + ci)*9 + k];
    }
    if (i < 9216) {                // 2304 * 4
        int o = i & 3, q = i >> 2;
        int cg = q & 7, t2 = q >> 3;
        int ci = t2 & 31, k = t2 >> 5;
        int oc = cg*4 + o;
        Wzt[i] = Wz[((size_t)oc*32 + ci)*9 + k];
    }
}

// Stage 16 channels of an 18x18 halo tile into LDS [pix][16ch] (pitch 20).
// Branchless clamped loads (always valid address, select to 0 outside) so all
// global loads pipeline; 4 channels packed into one ds_write_b128 (conflict-minimal).
__device__ __forceinline__ void stage16(float* tile,
    const float* __restrict__ src, size_t cstride, int h0, int w0, int tid)
{
    #pragma unroll
    for (int it = 0; it < 3; ++it) {
        int idx = it*512 + tid;        // 1296 float4s total
        if (idx < 1296) {
            int ci4 = idx / 324;       // 0..3  (channel quad)
            int pix = idx - ci4*324;   // 0..323
            int rr = pix / 18, cc = pix - rr*18;
            int gh = h0 + rr - 1, gw = w0 + cc - 1;
            int inb = (int)((unsigned)gh < 64u) & (int)((unsigned)gw < 64u);
            int ghc = min(max(gh, 0), HH-1), gwc = min(max(gw, 0), WW-1);
            const float* p = src + (size_t)(ci4*4)*cstride + (ghc*WW + gwc);
            float a0 = p[0];
            float a1 = p[cstride];
            float a2 = p[2*cstride];
            float a3 = p[3*cstride];
            float4 q;
            q.x = inb ? a0 : 0.0f;
            q.y = inb ? a1 : 0.0f;
            q.z = inb ? a2 : 0.0f;
            q.w = inb ? a3 : 0.0f;
            *(float4*)&tile[pix*PITCH + ci4*4] = q;
        }
    }
}

// Kernel A: xconv (4 gates) + yconv (3 gates) + Z update; writes Z, ms2, xy.
// 512 threads: two 256-thread halves compute two channel-groups off ONE staged tile.
__global__ __launch_bounds__(512, 4) void lem_gates(
    const float* __restrict__ X,
    const float* __restrict__ Wxt, const float* __restrict__ bx,
    const float* __restrict__ Wyt, const float* __restrict__ by,
    const float* __restrict__ Y, float* __restrict__ Z,
    float* __restrict__ ms2w, float* __restrict__ xyw, int t)
{
    __shared__ __align__(16) float tile[324*PITCH];   // 25,920 B
    const int tid = threadIdx.x;
    const int tx = tid & 15, ty = (tid >> 4) & 15;
    const int half = __builtin_amdgcn_readfirstlane(tid >> 8);  // wave-uniform 0/1
    const int w0 = blockIdx.x * 16, h0 = blockIdx.y * 16;
    const int b  = blockIdx.z >> 2;
    const int cg = ((blockIdx.z & 3) << 1) | half;    // 0..7 output channel group

    float ax[16], ay[12];
    #pragma unroll
    for (int i = 0; i < 16; i++) ax[i] = 0.0f;
    #pragma unroll
    for (int i = 0; i < 12; i++) ay[i] = 0.0f;

    // ---- x-conv: two 16-channel chunks ----
    const float* xb = X + ((size_t)b*CIN*NT + t)*HW;
    #pragma unroll
    for (int c = 0; c < 2; ++c) {
        stage16(tile, xb + (size_t)(c*16)*CSX, CSX, h0, w0, tid);
        __syncthreads();
        for (int k = 0; k < 9; ++k) {
            int kh = k/3, kw = k - kh*3;
            const float* lp = &tile[((ty+kh)*18 + tx+kw)*PITCH];
            const float* wp = Wxt + ((size_t)((k*32 + c*16)*8) + cg)*16;
            #pragma unroll
            for (int ci4 = 0; ci4 < 4; ++ci4) {
                float4 xv = *(const float4*)(lp + ci4*4);
                #pragma unroll
                for (int j = 0; j < 4; ++j) {
                    float v = (j==0)?xv.x:(j==1)?xv.y:(j==2)?xv.z:xv.w;
                    const float4* wr = (const float4*)(wp + (size_t)(ci4*4+j)*128);
                    #pragma unroll
                    for (int g = 0; g < 4; ++g) {
                        float4 wg = wr[g];
                        ax[g*4+0] = fmaf(v, wg.x, ax[g*4+0]);
                        ax[g*4+1] = fmaf(v, wg.y, ax[g*4+1]);
                        ax[g*4+2] = fmaf(v, wg.z, ax[g*4+2]);
                        ax[g*4+3] = fmaf(v, wg.w, ax[g*4+3]);
                    }
                }
            }
        }
        __syncthreads();
    }

    // ---- y-conv: two 16-channel chunks ----
    const float* yb = Y + (size_t)b*COUT*HW;
    #pragma unroll
    for (int c = 0; c < 2; ++c) {
        stage16(tile, yb + (size_t)(c*16)*HW, (size_t)HW, h0, w0, tid);
        __syncthreads();
        for (int k = 0; k < 9; ++k) {
            int kh = k/3, kw = k - kh*3;
            const float* lp = &tile[((ty+kh)*18 + tx+kw)*PITCH];
            const float* wp = Wyt + ((size_t)((k*32 + c*16)*8) + cg)*12;
            #pragma unroll
            for (int ci4 = 0; ci4 < 4; ++ci4) {
                float4 xv = *(const float4*)(lp + ci4*4);
                #pragma unroll
                for (int j = 0; j < 4; ++j) {
                    float v = (j==0)?xv.x:(j==1)?xv.y:(j==2)?xv.z:xv.w;
                    const float4* wr = (const float4*)(wp + (size_t)(ci4*4+j)*96);
                    #pragma unroll
                    for (int g = 0; g < 3; ++g) {
                        float4 wg = wr[g];
                        ay[g*4+0] = fmaf(v, wg.x, ay[g*4+0]);
                        ay[g*4+1] = fmaf(v, wg.y, ay[g*4+1]);
                        ay[g*4+2] = fmaf(v, wg.z, ay[g*4+2]);
                        ay[g*4+3] = fmaf(v, wg.w, ay[g*4+3]);
                    }
                }
            }
        }
        __syncthreads();
    }

    // ---- pointwise: Z update + stash ms2/xy ----
    const int h = h0 + ty, w = w0 + tx;
    #pragma unroll
    for (int ch = 0; ch < 4; ++ch) {
        int c = cg*4 + ch;
        size_t si = ((size_t)(b*COUT + c))*HW + h*WW + w;
        float g1 = ax[0+ch]  + bx[c]        + ay[0+ch] + by[c];
        float g2 = ax[4+ch]  + bx[COUT+c]   + ay[4+ch] + by[COUT+c];
        float zc = ax[8+ch]  + bx[2*COUT+c] + ay[8+ch] + by[2*COUT+c];
        float xy = ax[12+ch] + bx[3*COUT+c];
        float m1 = fsigmoid(g1);
        float zn = (1.0f - m1) * Z[si] + m1 * ftanh(zc);
        Z[si]    = zn;
        ms2w[si] = fsigmoid(g2);
        xyw[si]  = xy;
    }
}

// Kernel B: conv(Z_new, Wz) + Y update; writes Y and out[:, :, t]
__global__ __launch_bounds__(512, 4) void lem_update(
    const float* __restrict__ Wzt, const float* __restrict__ bz,
    const float* __restrict__ Z, float* __restrict__ Y,
    const float* __restrict__ ms2w, const float* __restrict__ xyw,
    float* __restrict__ out, int t)
{
    __shared__ __align__(16) float tile[324*PITCH];
    const int tid = threadIdx.x;
    const int tx = tid & 15, ty = (tid >> 4) & 15;
    const int half = __builtin_amdgcn_readfirstlane(tid >> 8);
    const int w0 = blockIdx.x * 16, h0 = blockIdx.y * 16;
    const int b  = blockIdx.z >> 2;
    const int cg = ((blockIdx.z & 3) << 1) | half;

    float az[4] = {0.f, 0.f, 0.f, 0.f};

    const float* zb = Z + (size_t)b*COUT*HW;
    #pragma unroll
    for (int c = 0; c < 2; ++c) {
        stage16(tile, zb + (size_t)(c*16)*HW, (size_t)HW, h0, w0, tid);
        __syncthreads();
        for (int k = 0; k < 9; ++k) {
            int kh = k/3, kw = k - kh*3;
            const float* lp = &tile[((ty+kh)*18 + tx+kw)*PITCH];
            const float* wp = Wzt + ((size_t)((k*32 + c*16)*8) + cg)*4;
            #pragma unroll
            for (int ci4 = 0; ci4 < 4; ++ci4) {
                float4 xv = *(const float4*)(lp + ci4*4);
                #pragma unroll
                for (int j = 0; j < 4; ++j) {
                    float v = (j==0)?xv.x:(j==1)?xv.y:(j==2)?xv.z:xv.w;
                    float4 wg = *(const float4*)(wp + (size_t)(ci4*4+j)*32);
                    az[0] = fmaf(v, wg.x, az[0]);
                    az[1] = fmaf(v, wg.y, az[1]);
                    az[2] = fmaf(v, wg.z, az[2]);
                    az[3] = fmaf(v, wg.w, az[3]);
                }
            }
        }
        __syncthreads();
    }

    const int h = h0 + ty, w = w0 + tx;
    #pragma unroll
    for (int ch = 0; ch < 4; ++ch) {
        int c = cg*4 + ch;
        size_t si = ((size_t)(b*COUT + c))*HW + h*WW + w;
        float m2 = ms2w[si];
        float yn = (1.0f - m2) * Y[si] + m2 * ftanh(xyw[si] + az[ch] + bz[c]);
        Y[si] = yn;
        out[((size_t)(b*COUT + c)*NT + t)*HW + h*WW + w] = yn;
    }
}

extern "C" void kernel_launch(void* const* d_in, const int* in_sizes, int n_in,
                              void* d_out, int out_size, void* d_ws, size_t ws_size,
                              hipStream_t stream)
{
    const float* X  = (const float*)d_in[0];
    const float* Wx = (const float*)d_in[1];
    const float* bx = (const float*)d_in[2];
    const float* Wy = (const float*)d_in[3];
    const float* by = (const float*)d_in[4];
    const float* Wz = (const float*)d_in[5];
    const float* bz = (const float*)d_in[6];
    float* out = (float*)d_out;
    float* ws  = (float*)d_ws;

    const size_t S = (size_t)NB*COUT*HW;  // 1,048,576 elems per state tensor
    float* Y   = ws;
    float* Z   = ws + S;
    float* m2w = ws + 2*S;
    float* xyw = ws + 3*S;
    float* Wxt = ws + 4*S;                 // 36864
    float* Wyt = Wxt + 36864;              // 27648
    float* Wzt = Wyt + 27648;              // 9216

    hipMemsetAsync(Y, 0, 2*S*sizeof(float), stream);
    wtrans<<<dim3(144), dim3(256), 0, stream>>>(Wx, Wy, Wz, Wxt, Wyt, Wzt);

    dim3 grid(WW/16, HH/16, NB*4);   // 512 blocks of 512 threads
    for (int t = 0; t < NT; t++) {
        lem_gates <<<grid, 512, 0, stream>>>(X, Wxt, bx, Wyt, by, Y, Z, m2w, xyw, t);
        lem_update<<<grid, 512, 0, stream>>>(Wzt, bz, Z, Y, m2w, xyw, out, t);
    }
}